// Round 18
// baseline (583.160 us; speedup 1.0000x reference)
//
#include <hip/hip_runtime.h>
#include <math.h>

#define NN 100000
#define EIN 800000
#define EEX 400000
#define ND 35
#define H 128
#define NG 256
#define NL 4
#define TM 16          // nodes per tile (MFMA M)
#define TML 16         // nodes per block in lin_node
#define NTILES 6250    // NN/TM
// padded CSR capacities (each node's range rounded up to multiple of 4)
#define EINP (EIN + 4*NN)
#define EEXP (EEX + 4*NN)

typedef unsigned short u16;
typedef unsigned char u8;
typedef short s8v __attribute__((ext_vector_type(8)));   // 8 bf16 (4 VGPRs)
typedef float f4v __attribute__((ext_vector_type(4)));   // 4 fp32 acc
typedef float f2v __attribute__((ext_vector_type(2)));

__device__ __forceinline__ float silu_f(float x){ return x / (1.0f + __expf(-x)); }
__device__ __forceinline__ float bf2f(u16 v){ return __uint_as_float(((unsigned)v) << 16); }
__device__ __forceinline__ u16 f2bf(float f){
  unsigned u = __float_as_uint(f);
  u += 0x7FFFu + ((u >> 16) & 1u);   // RNE
  return (u16)(u >> 16);
}
__device__ __forceinline__ u8 f2fp8(float f){
  int p = __builtin_amdgcn_cvt_pk_fp8_f32(f, f, 0, false);   // OCP e4m3 on gfx950
  return (u8)(p & 0xff);
}

// ---------------- merged prep: wfrag (blocks 0..7) + MFMA lin_node + degree count ----------------
__global__ __launch_bounds__(256) void k_prep(const float* __restrict__ x,
                                              const float* __restrict__ lnW,
                                              const float* __restrict__ lnb,
                                              u16* __restrict__ h,
                                              u8* __restrict__ h8,
                                              const float* __restrict__ WI,
                                              const float* __restrict__ WE,
                                              u16* __restrict__ WfI,
                                              u16* __restrict__ WfE,
                                              const int* __restrict__ dst_i,
                                              const int* __restrict__ dst_e,
                                              int* __restrict__ cnt_i,
                                              int* __restrict__ cnt_e){
  const int NBW = 2*NL;          // 8 weight-swizzle blocks
  const int NBL = NN/TML;        // 6250 lin_node blocks
  if (blockIdx.x < NBW){
    const int lm = blockIdx.x;
    const int l = lm >> 1;
    const float* src = (lm & 1) ? (WE + (size_t)l*H*H) : (WI + (size_t)l*H*H);
    u16* dst = ((lm & 1) ? WfE : WfI) + (size_t)l*H*H;
    for (int idx = threadIdx.x; idx < H*H; idx += 256){
      const int r = idx & 7, lane = (idx>>3)&63, kc = (idx>>9)&3, jt = idx>>11;
      const int k = kc*32 + (lane>>4)*8 + r;
      const int j = jt*16 + (lane&15);
      dst[idx] = f2bf(src[k*H + j]);
    }
    return;
  }
  if (blockIdx.x < NBW + NBL){
    // ---- MFMA lin_node: h = silu(x @ lnW + lnb), 16 nodes/block ----
    __shared__ u16 xs[TM][72];   // row pad 72: 2-way bank alias only (free, m136)
    const int n0 = (blockIdx.x - NBW) * TML;
    const int tid = threadIdx.x;
    for (int i = tid; i < TM*64; i += 256){
      const int m = i >> 6, k = i & 63;
      xs[m][k] = (k < ND) ? f2bf(x[(size_t)(n0+m)*ND + k]) : (u16)0;
    }
    __syncthreads();
    const int lane = tid & 63;
    const int wv   = tid >> 6;
    const int col  = lane & 15;
    const int quad = lane >> 4;
    const int jta = 2*wv, jtb = 2*wv + 1;
    const int ja = jta*16 + col, jb = jtb*16 + col;

    f4v accA = {0.f,0.f,0.f,0.f}, accB = {0.f,0.f,0.f,0.f};
    #pragma unroll
    for (int kc = 0; kc < 2; ++kc){
      const s8v a = *(const s8v*)&xs[col][kc*32 + quad*8];
      s8v bA, bB;
      #pragma unroll
      for (int r = 0; r < 8; ++r){
        const int k = kc*32 + quad*8 + r;
        bA[r] = (k < ND) ? (short)f2bf(lnW[k*H + ja]) : (short)0;
        bB[r] = (k < ND) ? (short)f2bf(lnW[k*H + jb]) : (short)0;
      }
      accA = __builtin_amdgcn_mfma_f32_16x16x32_bf16(a, bA, accA, 0, 0, 0);
      accB = __builtin_amdgcn_mfma_f32_16x16x32_bf16(a, bB, accB, 0, 0, 0);
    }
    const float bja = lnb[ja], bjb = lnb[jb];
    #pragma unroll
    for (int r = 0; r < 4; ++r){
      const int n = n0 + quad*4 + r;           // C/D: col=lane&15, row=quad*4+reg (m89)
      const float ha = silu_f(accA[r] + bja);
      const float hb = silu_f(accB[r] + bjb);
      h[(size_t)n*H + ja] = f2bf(ha);
      h[(size_t)n*H + jb] = f2bf(hb);
      h8[(size_t)n*H + ja] = f2fp8(ha);
      h8[(size_t)n*H + jb] = f2fp8(hb);
    }
    return;
  }
  // degree count
  int e = (blockIdx.x - NBW - NBL)*256 + threadIdx.x;
  if (e < EIN) atomicAdd(&cnt_i[dst_i[e]], 1);
  else if (e < EIN + EEX) atomicAdd(&cnt_e[dst_e[e - EIN]], 1);
}

// ---------------- single-pass CSR scan, ranges padded to multiples of 4 ----------------
// Padding makes every node's CSR base 16B-aligned so the gather can use int4/float4
// edge-list loads. Gap slots are never read (gather bounds by cnt).
__global__ void k_scan_fused(const int* __restrict__ cnt_i, const int* __restrict__ cnt_e,
                             int* __restrict__ row_i, int* __restrict__ cur_i,
                             int* __restrict__ row_e, int* __restrict__ cur_e,
                             int* __restrict__ cursors){
  __shared__ int s[256];
  __shared__ int basev;
  const int NB = (NN + 255)/256;
  const bool inter = (int)blockIdx.x >= NB;
  const int* cnt = inter ? cnt_e : cnt_i;
  int* rowp = inter ? row_e : row_i;
  int* curp = inter ? cur_e : cur_i;
  int* cursor = cursors + (inter ? 1 : 0);
  const int b = inter ? blockIdx.x - NB : blockIdx.x;
  const int t = threadIdx.x;
  const int i = b*256 + t;
  int v = (i < NN) ? cnt[i] : 0;
  int vp4 = (v + 3) & ~3;                 // padded size
  s[t] = vp4; __syncthreads();
  for (int o = 1; o < 256; o <<= 1){
    int a = (t >= o) ? s[t-o] : 0;
    __syncthreads();
    s[t] += a;
    __syncthreads();
  }
  if (t == 255) basev = atomicAdd(cursor, s[255]);
  __syncthreads();
  if (i < NN){
    int ex = basev + s[t] - vp4;
    rowp[i] = ex; curp[i] = ex;
  }
}

// ---------------- combined CSR fill ----------------
__global__ void k_fill_all(const int* __restrict__ src_i, const int* __restrict__ dst_i,
                           const float* __restrict__ ea,
                           const int* __restrict__ src_e, const int* __restrict__ dst_e,
                           const float* __restrict__ pos,
                           int* __restrict__ cur_i, int* __restrict__ col_i, float* __restrict__ val_i,
                           int* __restrict__ cur_e, int* __restrict__ col_e, float* __restrict__ val_e){
  int e = blockIdx.x*256 + threadIdx.x;
  if (e < EIN){
    int d = dst_i[e];
    int slot = atomicAdd(&cur_i[d], 1);
    col_i[slot] = src_i[e];
    val_i[slot] = ea[e];
  } else if (e < EIN + EEX){
    int ee = e - EIN;
    int s = src_e[ee], d = dst_e[ee];
    float dx = pos[3*s+0] - pos[3*d+0];
    float dy = pos[3*s+1] - pos[3*d+1];
    float dz = pos[3*s+2] - pos[3*d+2];
    float w = __expf(-(dx*dx + dy*dy + dz*dz));
    int slot = atomicAdd(&cur_e[d], 1);
    col_e[slot] = s;
    val_e[slot] = w;
  }
}

// ---------------- gather (fp8 mirror, vector edge-list loads, packed f32 FMA) ----------------
#define GATHER8_BODY                                                                  \
  {                                                                                   \
    const int slot = tid >> 4;                                                        \
    const int l16  = tid & 15;                                                        \
    const int j8 = l16 * 8;                                                           \
    const int n = n0 + slot;                                                          \
    _Pragma("unroll")                                                                 \
    for (int list = 0; list < 2; ++list){                                             \
      const int*   rowp = list ? rowE : rowI;                                         \
      const int*   cntp = list ? cntE : cntI;                                         \
      const int*   colp = list ? colE : colI;                                         \
      const float* valp = list ? valE : valI;                                         \
      f2v a01 = {0.f,0.f}, a23 = {0.f,0.f}, a45 = {0.f,0.f}, a67 = {0.f,0.f};         \
      const int s = rowp[n], c = cntp[n];                                             \
      int t = 0;                                                                      \
      for (; t + 4 <= c; t += 4){                                                     \
        const int4   cc = *(const int4*)  (colp + s + t);   /* s,t mult of 4 */       \
        const float4 vv = *(const float4*)(valp + s + t);                             \
        uint2 qq[4];                                                                  \
        qq[0] = *(const uint2*)(hin8 + (size_t)cc.x*H + j8);                          \
        qq[1] = *(const uint2*)(hin8 + (size_t)cc.y*H + j8);                          \
        qq[2] = *(const uint2*)(hin8 + (size_t)cc.z*H + j8);                          \
        qq[3] = *(const uint2*)(hin8 + (size_t)cc.w*H + j8);                          \
        const float vvv[4] = {vv.x, vv.y, vv.z, vv.w};                                \
        _Pragma("unroll")                                                             \
        for (int u = 0; u < 4; ++u){                                                  \
          const f2v x01 = __builtin_amdgcn_cvt_pk_f32_fp8((int)qq[u].x, false);       \
          const f2v x23 = __builtin_amdgcn_cvt_pk_f32_fp8((int)qq[u].x, true);        \
          const f2v x45 = __builtin_amdgcn_cvt_pk_f32_fp8((int)qq[u].y, false);       \
          const f2v x67 = __builtin_amdgcn_cvt_pk_f32_fp8((int)qq[u].y, true);        \
          a01 += x01 * vvv[u];                                                        \
          a23 += x23 * vvv[u];                                                        \
          a45 += x45 * vvv[u];                                                        \
          a67 += x67 * vvv[u];                                                        \
        }                                                                             \
      }                                                                               \
      for (; t < c; ++t){                                                             \
        const int c0 = colp[s+t];                                                     \
        const float v0 = valp[s+t];                                                   \
        const uint2 q0 = *(const uint2*)(hin8 + (size_t)c0*H + j8);                   \
        const f2v x01 = __builtin_amdgcn_cvt_pk_f32_fp8((int)q0.x, false);            \
        const f2v x23 = __builtin_amdgcn_cvt_pk_f32_fp8((int)q0.x, true);             \
        const f2v x45 = __builtin_amdgcn_cvt_pk_f32_fp8((int)q0.y, false);            \
        const f2v x67 = __builtin_amdgcn_cvt_pk_f32_fp8((int)q0.y, true);             \
        a01 += x01 * v0;                                                              \
        a23 += x23 * v0;                                                              \
        a45 += x45 * v0;                                                              \
        a67 += x67 * v0;                                                              \
      }                                                                               \
      const unsigned p0 = (unsigned)f2bf(a01.x) | ((unsigned)f2bf(a01.y) << 16);      \
      const unsigned p1 = (unsigned)f2bf(a23.x) | ((unsigned)f2bf(a23.y) << 16);      \
      const unsigned p2 = (unsigned)f2bf(a45.x) | ((unsigned)f2bf(a45.y) << 16);      \
      const unsigned p3 = (unsigned)f2bf(a67.x) | ((unsigned)f2bf(a67.y) << 16);      \
      u16* drow = list ? &aggEs[slot][j8] : &aggIs[slot][j8];                         \
      *(uint4*)drow = make_uint4(p0, p1, p2, p3);                                     \
    }                                                                                 \
  }

#define MFMA_BODY                                                                     \
  f4v accIA = {0.f,0.f,0.f,0.f}, accIB = {0.f,0.f,0.f,0.f};                           \
  f4v accEA = {0.f,0.f,0.f,0.f}, accEB = {0.f,0.f,0.f,0.f};                           \
  _Pragma("unroll")                                                                   \
  for (int kc = 0; kc < 4; ++kc){                                                     \
    const int koff = kc*32 + quad*8;                                                  \
    const s8v aI = *(const s8v*)&aggIs[col][koff];                                    \
    const s8v aE = *(const s8v*)&aggEs[col][koff];                                    \
    const s8v bIA = *(const s8v*)(WfI + (((jta*4 + kc)*64 + lane) << 3));             \
    const s8v bIB = *(const s8v*)(WfI + (((jtb*4 + kc)*64 + lane) << 3));             \
    const s8v bEA = *(const s8v*)(WfE + (((jta*4 + kc)*64 + lane) << 3));             \
    const s8v bEB = *(const s8v*)(WfE + (((jtb*4 + kc)*64 + lane) << 3));             \
    accIA = __builtin_amdgcn_mfma_f32_16x16x32_bf16(aI, bIA, accIA, 0, 0, 0);         \
    accIB = __builtin_amdgcn_mfma_f32_16x16x32_bf16(aI, bIB, accIB, 0, 0, 0);         \
    accEA = __builtin_amdgcn_mfma_f32_16x16x32_bf16(aE, bEA, accEA, 0, 0, 0);         \
    accEB = __builtin_amdgcn_mfma_f32_16x16x32_bf16(aE, bEB, accEB, 0, 0, 0);         \
  }

// ---------------- layers 1..2: read state, write hout + fp8 mirror ----------------
__global__ __launch_bounds__(256) void k_layer(
    const u16* __restrict__ hin, const u8* __restrict__ hin8,
    u16* __restrict__ hout, u8* __restrict__ hout8,
    u16* __restrict__ vp, u16* __restrict__ vl,
    const int* __restrict__ rowI, const int* __restrict__ cntI,
    const int* __restrict__ colI, const float* __restrict__ valI,
    const int* __restrict__ rowE, const int* __restrict__ cntE,
    const int* __restrict__ colE, const float* __restrict__ valE,
    const u16* __restrict__ WfI, const float* __restrict__ bI,
    const u16* __restrict__ WfE, const float* __restrict__ bE)
{
  __shared__ u16 aggIs[TM][136];
  __shared__ u16 aggEs[TM][136];
  const int n0 = blockIdx.x * TM;
  const int tid = threadIdx.x;

  GATHER8_BODY
  __syncthreads();

  const int lane = tid & 63;
  const int w    = tid >> 6;
  const int jta = 2*w, jtb = 2*w + 1;
  const int col  = lane & 15;
  const int quad = lane >> 4;
  MFMA_BODY

  #pragma unroll
  for (int r = 0; r < 4; ++r){
    const int m = quad*4 + r;
    const int n = n0 + m;
    const float cI = (float)cntI[n];
    const float cE = (float)cntE[n];
    const float rdI = 1.0f / (cI + 1.0f);
    const float ldE = logf(cE + 1.0f);
    #pragma unroll
    for (int half = 0; half < 2; ++half){
      const int j = (half ? jtb : jta)*16 + col;
      const float aIv = half ? accIB[r] : accIA[r];
      const float aEv = half ? accEB[r] : accEA[r];
      const float mi = (aIv + cI*bI[j]) * rdI;
      const float me = (aEv + cE*bE[j]) * ldE;
      const size_t idx = (size_t)n*H + j;
      const float vpn = silu_f(mi + bf2f(vp[idx]));
      const float vln = silu_f(me + bf2f(vl[idx]));
      vp[idx] = f2bf(vpn); vl[idx] = f2bf(vln);
      const float hnew = bf2f(hin[idx]) + vpn + vln;
      hout[idx] = f2bf(hnew);
      hout8[idx] = f2fp8(hnew);
    }
  }
}

// ---------------- layer 0: state store-only (no vp/vl read, no memset needed) ----------------
__global__ __launch_bounds__(256) void k_layer0(
    const u16* __restrict__ hin, const u8* __restrict__ hin8,
    u16* __restrict__ hout, u8* __restrict__ hout8,
    u16* __restrict__ vp, u16* __restrict__ vl,
    const int* __restrict__ rowI, const int* __restrict__ cntI,
    const int* __restrict__ colI, const float* __restrict__ valI,
    const int* __restrict__ rowE, const int* __restrict__ cntE,
    const int* __restrict__ colE, const float* __restrict__ valE,
    const u16* __restrict__ WfI, const float* __restrict__ bI,
    const u16* __restrict__ WfE, const float* __restrict__ bE)
{
  __shared__ u16 aggIs[TM][136];
  __shared__ u16 aggEs[TM][136];
  const int n0 = blockIdx.x * TM;
  const int tid = threadIdx.x;

  GATHER8_BODY
  __syncthreads();

  const int lane = tid & 63;
  const int w    = tid >> 6;
  const int jta = 2*w, jtb = 2*w + 1;
  const int col  = lane & 15;
  const int quad = lane >> 4;
  MFMA_BODY

  #pragma unroll
  for (int r = 0; r < 4; ++r){
    const int m = quad*4 + r;
    const int n = n0 + m;
    const float cI = (float)cntI[n];
    const float cE = (float)cntE[n];
    const float rdI = 1.0f / (cI + 1.0f);
    const float ldE = logf(cE + 1.0f);
    #pragma unroll
    for (int half = 0; half < 2; ++half){
      const int j = (half ? jtb : jta)*16 + col;
      const float aIv = half ? accIB[r] : accIA[r];
      const float aEv = half ? accEB[r] : accEA[r];
      const float mi = (aIv + cI*bI[j]) * rdI;
      const float me = (aEv + cE*bE[j]) * ldE;
      const size_t idx = (size_t)n*H + j;
      const float vpn = silu_f(mi);      // vp/vl start at zero: no read
      const float vln = silu_f(me);
      vp[idx] = f2bf(vpn); vl[idx] = f2bf(vln);
      const float hnew = bf2f(hin[idx]) + vpn + vln;
      hout[idx] = f2bf(hnew);
      hout8[idx] = f2fp8(hnew);
    }
  }
}

// ---------------- layer 3: NO state stores; pool fused from registers ----------------
__global__ __launch_bounds__(256) void k_layer3(
    const u16* __restrict__ hin, const u8* __restrict__ hin8,
    u16* __restrict__ vp, u16* __restrict__ vl,
    const int* __restrict__ rowI, const int* __restrict__ cntI,
    const int* __restrict__ colI, const float* __restrict__ valI,
    const int* __restrict__ rowE, const int* __restrict__ cntE,
    const int* __restrict__ colE, const float* __restrict__ valE,
    const u16* __restrict__ WfI, const float* __restrict__ bI,
    const u16* __restrict__ WfE, const float* __restrict__ bE,
    const int* __restrict__ batch, float* __restrict__ gp)
{
  __shared__ u16 aggIs[TM][136];
  __shared__ u16 aggEs[TM][136];
  const int n0 = blockIdx.x * TM;
  const int tid = threadIdx.x;

  GATHER8_BODY
  __syncthreads();

  const int lane = tid & 63;
  const int w    = tid >> 6;
  const int jta = 2*w, jtb = 2*w + 1;
  const int col  = lane & 15;
  const int quad = lane >> 4;
  MFMA_BODY

  float hf0[4], hf1[4];
  #pragma unroll
  for (int r = 0; r < 4; ++r){
    const int m = quad*4 + r;
    const int n = n0 + m;
    const float cI = (float)cntI[n];
    const float cE = (float)cntE[n];
    const float rdI = 1.0f / (cI + 1.0f);
    const float ldE = logf(cE + 1.0f);
    const int j0 = jta*16 + col;
    const int j1 = jtb*16 + col;
    const size_t i0 = (size_t)n*H + j0;
    const size_t i1 = (size_t)n*H + j1;
    const float mi0 = (accIA[r] + cI*bI[j0]) * rdI;
    const float me0 = (accEA[r] + cE*bE[j0]) * ldE;
    const float mi1 = (accIB[r] + cI*bI[j1]) * rdI;
    const float me1 = (accEB[r] + cE*bE[j1]) * ldE;
    const float vpn0 = silu_f(mi0 + bf2f(vp[i0]));
    const float vln0 = silu_f(me0 + bf2f(vl[i0]));
    const float vpn1 = silu_f(mi1 + bf2f(vp[i1]));
    const float vln1 = silu_f(me1 + bf2f(vl[i1]));
    hf0[r] = bf2f(hin[i0]) + vpn0 + vln0;
    hf1[r] = bf2f(hin[i1]) + vpn1 + vln1;
  }

  const int j0g = jta*16 + col;
  const int j1g = jtb*16 + col;
  const int b0 = batch[n0];
  const int b15 = batch[n0 + TM - 1];
  if (b0 == b15){
    float s0 = hf0[0] + hf0[1] + hf0[2] + hf0[3];
    float s1 = hf1[0] + hf1[1] + hf1[2] + hf1[3];
    s0 += __shfl_xor(s0, 16, 64); s0 += __shfl_xor(s0, 32, 64);
    s1 += __shfl_xor(s1, 16, 64); s1 += __shfl_xor(s1, 32, 64);
    if (quad == 0){
      atomicAdd(&gp[(size_t)b0*H + j0g], s0);
      atomicAdd(&gp[(size_t)b0*H + j1g], s1);
    }
  } else {
    #pragma unroll
    for (int r = 0; r < 4; ++r){
      const int bcur = batch[n0 + quad*4 + r];
      atomicAdd(&gp[(size_t)bcur*H + j0g], hf0[r]);
      atomicAdd(&gp[(size_t)bcur*H + j1g], hf1[r]);
    }
  }
}

// ---------------- FC head ----------------
__global__ void k_fc(const float* __restrict__ g, const float* __restrict__ fcW,
                     const float* __restrict__ fcb, const float* __restrict__ gamma,
                     const float* __restrict__ beta, const float* __restrict__ outW,
                     const float* __restrict__ outb, float* __restrict__ out){
  __shared__ float row[H];
  __shared__ float red[H];
  const int gi = blockIdx.x;
  const int j = threadIdx.x;
  row[j] = g[(size_t)gi*H + j];
  __syncthreads();
  const float bn_scale = rsqrtf(1.0f + 1e-5f);
  for (int l = 0; l < 3; ++l){
    const float* W = fcW + (size_t)l*H*H;
    float acc = fcb[l*H + j];
    #pragma unroll 8
    for (int k = 0; k < H; ++k) acc += row[k] * W[k*H + j];
    acc = (acc > 0.f) ? acc : 0.01f*acc;             // leaky_relu
    acc = acc * bn_scale * gamma[l*H + j] + beta[l*H + j];
    __syncthreads();
    row[j] = acc;
    __syncthreads();
  }
  red[j] = row[j] * outW[j];
  __syncthreads();
  for (int o = 64; o > 0; o >>= 1){
    if (j < o) red[j] += red[j + o];
    __syncthreads();
  }
  if (j == 0) out[gi] = red[0] + outb[0];
}

extern "C" void kernel_launch(void* const* d_in, const int* in_sizes, int n_in,
                              void* d_out, int out_size, void* d_ws, size_t ws_size,
                              hipStream_t stream)
{
  const float* x    = (const float*)d_in[0];
  const int*   eii  = (const int*)  d_in[1];
  const int*   eie  = (const int*)  d_in[2];
  const float* pos  = (const float*)d_in[3];
  const float* ea   = (const float*)d_in[4];
  const int*   batch= (const int*)  d_in[5];
  const float* lnW  = (const float*)d_in[6];
  const float* lnb  = (const float*)d_in[7];
  const float* WIa  = (const float*)d_in[8];
  const float* bIa  = (const float*)d_in[9];
  const float* WEa  = (const float*)d_in[10];
  const float* bEa  = (const float*)d_in[11];
  const float* fcW  = (const float*)d_in[12];
  const float* fcb  = (const float*)d_in[13];
  const float* gam  = (const float*)d_in[14];
  const float* bet  = (const float*)d_in[15];
  const float* outW = (const float*)d_in[16];
  const float* outb = (const float*)d_in[17];
  float* out = (float*)d_out;

  const int* src_i = eii;  const int* dst_i = eii + EIN;
  const int* src_e = eie;  const int* dst_e = eie + EEX;

  const size_t NH = (size_t)NN * H;
  u16* hA = (u16*)d_ws;                    // NH
  u16* hB = hA + NH;
  u16* vp = hB + NH;
  u16* vl = vp + NH;
  u8* hA8 = (u8*)(vl + NH);                // NH bytes
  u8* hB8 = hA8 + NH;
  float* gp = (float*)(hB8 + NH);          // NG*H
  int* cnt_i = (int*)(gp + (size_t)NG*H);  // NN
  int* cnt_e = cnt_i + NN;
  int* cursors = cnt_e + NN;               // 4 ints
  int* row_i = cursors + 4;
  int* row_e = row_i + NN;
  int* cur_i = row_e + NN;
  int* cur_e = cur_i + NN;
  int* col_i = cur_e + NN;                 // EINP (padded)
  float* val_i = (float*)(col_i + EINP);   // EINP
  int* col_e = (int*)(val_i + EINP);       // EEXP
  float* val_e = (float*)(col_e + EEXP);   // EEXP
  u16* WfI = (u16*)(val_e + EEXP);         // NL*H*H bf16
  u16* WfE = WfI + (size_t)NL*H*H;

  const size_t need = 4*NH*sizeof(u16) + 2*NH
                    + ((size_t)NG*H + 6*(size_t)NN + 4 + 2*(size_t)EINP + 2*(size_t)EEXP)*4
                    + 2*(size_t)NL*H*H*sizeof(u16);
  if (ws_size < need) return;

  // memset: gp + cnt_i + cnt_e + cursors (contiguous)
  hipMemsetAsync(gp, 0, ((size_t)NG*H + 2*(size_t)NN + 4)*sizeof(int), stream);

  const int NE_ALL = EIN + EEX;
  const int NBC = (NE_ALL + 255)/256;      // 4688 count blocks
  k_prep<<<2*NL + NN/TML + NBC, 256, 0, stream>>>(x, lnW, lnb, hA, hA8, WIa, WEa, WfI, WfE,
                                                  dst_i, dst_e, cnt_i, cnt_e);

  const int NB = (NN + 255)/256;  // 391
  k_scan_fused<<<2*NB, 256, 0, stream>>>(cnt_i, cnt_e, row_i, cur_i, row_e, cur_e, cursors);
  k_fill_all<<<NBC, 256, 0, stream>>>(src_i, dst_i, ea, src_e, dst_e, pos,
                                      cur_i, col_i, val_i, cur_e, col_e, val_e);

  // L0: hA->hB ; L1: hB->hA ; L2: hA->hB ; L3: reads hB, pools into gp
  k_layer0<<<NTILES, 256, 0, stream>>>(hA, hA8, hB, hB8, vp, vl,
      row_i, cnt_i, col_i, val_i, row_e, cnt_e, col_e, val_e,
      WfI + 0*(size_t)H*H, bIa + 0*H, WfE + 0*(size_t)H*H, bEa + 0*H);
  k_layer<<<NTILES, 256, 0, stream>>>(hB, hB8, hA, hA8, vp, vl,
      row_i, cnt_i, col_i, val_i, row_e, cnt_e, col_e, val_e,
      WfI + 1*(size_t)H*H, bIa + 1*H, WfE + 1*(size_t)H*H, bEa + 1*H);
  k_layer<<<NTILES, 256, 0, stream>>>(hA, hA8, hB, hB8, vp, vl,
      row_i, cnt_i, col_i, val_i, row_e, cnt_e, col_e, val_e,
      WfI + 2*(size_t)H*H, bIa + 2*H, WfE + 2*(size_t)H*H, bEa + 2*H);
  k_layer3<<<NTILES, 256, 0, stream>>>(hB, hB8, vp, vl,
      row_i, cnt_i, col_i, val_i, row_e, cnt_e, col_e, val_e,
      WfI + 3*(size_t)H*H, bIa + 3*H, WfE + 3*(size_t)H*H, bEa + 3*H,
      batch, gp);

  k_fc<<<NG, H, 0, stream>>>(gp, fcW, fcb, gam, bet, outW, outb, out);
}

// Round 19
// 571.905 us; speedup vs baseline: 1.0197x; 1.0197x over previous
//
#include <hip/hip_runtime.h>
#include <math.h>

#define NN 100000
#define EIN 800000
#define EEX 400000
#define ND 35
#define H 128
#define NG 256
#define NL 4
#define TM 16          // nodes per tile (MFMA M)
#define TML 16         // nodes per block in lin_node
#define NTILES 6250    // NN/TM

typedef unsigned short u16;
typedef unsigned char u8;
typedef short s8v __attribute__((ext_vector_type(8)));   // 8 bf16 (4 VGPRs)
typedef float f4v __attribute__((ext_vector_type(4)));   // 4 fp32 acc
typedef float f2v __attribute__((ext_vector_type(2)));

__device__ __forceinline__ float silu_f(float x){ return x / (1.0f + __expf(-x)); }
__device__ __forceinline__ float bf2f(u16 v){ return __uint_as_float(((unsigned)v) << 16); }
__device__ __forceinline__ u16 f2bf(float f){
  unsigned u = __float_as_uint(f);
  u += 0x7FFFu + ((u >> 16) & 1u);   // RNE
  return (u16)(u >> 16);
}
__device__ __forceinline__ u8 f2fp8(float f){
  int p = __builtin_amdgcn_cvt_pk_fp8_f32(f, f, 0, false);   // OCP e4m3 on gfx950
  return (u8)(p & 0xff);
}

// ---------------- merged prep: wfrag (blocks 0..7) + MFMA lin_node + degree count ----------------
__global__ __launch_bounds__(256) void k_prep(const float* __restrict__ x,
                                              const float* __restrict__ lnW,
                                              const float* __restrict__ lnb,
                                              u16* __restrict__ h,
                                              u8* __restrict__ h8,
                                              const float* __restrict__ WI,
                                              const float* __restrict__ WE,
                                              u16* __restrict__ WfI,
                                              u16* __restrict__ WfE,
                                              const int* __restrict__ dst_i,
                                              const int* __restrict__ dst_e,
                                              int* __restrict__ cnt_i,
                                              int* __restrict__ cnt_e){
  const int NBW = 2*NL;          // 8 weight-swizzle blocks
  const int NBL = NN/TML;        // 6250 lin_node blocks
  if (blockIdx.x < NBW){
    const int lm = blockIdx.x;
    const int l = lm >> 1;
    const float* src = (lm & 1) ? (WE + (size_t)l*H*H) : (WI + (size_t)l*H*H);
    u16* dst = ((lm & 1) ? WfE : WfI) + (size_t)l*H*H;
    for (int idx = threadIdx.x; idx < H*H; idx += 256){
      const int r = idx & 7, lane = (idx>>3)&63, kc = (idx>>9)&3, jt = idx>>11;
      const int k = kc*32 + (lane>>4)*8 + r;
      const int j = jt*16 + (lane&15);
      dst[idx] = f2bf(src[k*H + j]);
    }
    return;
  }
  if (blockIdx.x < NBW + NBL){
    // ---- MFMA lin_node: h = silu(x @ lnW + lnb), 16 nodes/block ----
    __shared__ u16 xs[TM][72];   // row pad 72: 2-way bank alias only (free, m136)
    const int n0 = (blockIdx.x - NBW) * TML;
    const int tid = threadIdx.x;
    for (int i = tid; i < TM*64; i += 256){
      const int m = i >> 6, k = i & 63;
      xs[m][k] = (k < ND) ? f2bf(x[(size_t)(n0+m)*ND + k]) : (u16)0;
    }
    __syncthreads();
    const int lane = tid & 63;
    const int wv   = tid >> 6;
    const int col  = lane & 15;
    const int quad = lane >> 4;
    const int jta = 2*wv, jtb = 2*wv + 1;
    const int ja = jta*16 + col, jb = jtb*16 + col;

    f4v accA = {0.f,0.f,0.f,0.f}, accB = {0.f,0.f,0.f,0.f};
    #pragma unroll
    for (int kc = 0; kc < 2; ++kc){
      const s8v a = *(const s8v*)&xs[col][kc*32 + quad*8];
      s8v bA, bB;
      #pragma unroll
      for (int r = 0; r < 8; ++r){
        const int k = kc*32 + quad*8 + r;
        bA[r] = (k < ND) ? (short)f2bf(lnW[k*H + ja]) : (short)0;
        bB[r] = (k < ND) ? (short)f2bf(lnW[k*H + jb]) : (short)0;
      }
      accA = __builtin_amdgcn_mfma_f32_16x16x32_bf16(a, bA, accA, 0, 0, 0);
      accB = __builtin_amdgcn_mfma_f32_16x16x32_bf16(a, bB, accB, 0, 0, 0);
    }
    const float bja = lnb[ja], bjb = lnb[jb];
    #pragma unroll
    for (int r = 0; r < 4; ++r){
      const int n = n0 + quad*4 + r;           // C/D: col=lane&15, row=quad*4+reg (m89)
      const float ha = silu_f(accA[r] + bja);
      const float hb = silu_f(accB[r] + bjb);
      h[(size_t)n*H + ja] = f2bf(ha);
      h[(size_t)n*H + jb] = f2bf(hb);
      h8[(size_t)n*H + ja] = f2fp8(ha);
      h8[(size_t)n*H + jb] = f2fp8(hb);
    }
    return;
  }
  // degree count
  int e = (blockIdx.x - NBW - NBL)*256 + threadIdx.x;
  if (e < EIN) atomicAdd(&cnt_i[dst_i[e]], 1);
  else if (e < EIN + EEX) atomicAdd(&cnt_e[dst_e[e - EIN]], 1);
}

// ---------------- single-pass CSR scan: block base via atomic cursor ----------------
__global__ void k_scan_fused(const int* __restrict__ cnt_i, const int* __restrict__ cnt_e,
                             int* __restrict__ row_i, int* __restrict__ cur_i,
                             int* __restrict__ row_e, int* __restrict__ cur_e,
                             int* __restrict__ cursors){
  __shared__ int s[256];
  __shared__ int basev;
  const int NB = (NN + 255)/256;
  const bool inter = (int)blockIdx.x >= NB;
  const int* cnt = inter ? cnt_e : cnt_i;
  int* rowp = inter ? row_e : row_i;
  int* curp = inter ? cur_e : cur_i;
  int* cursor = cursors + (inter ? 1 : 0);
  const int b = inter ? blockIdx.x - NB : blockIdx.x;
  const int t = threadIdx.x;
  const int i = b*256 + t;
  int v = (i < NN) ? cnt[i] : 0;
  s[t] = v; __syncthreads();
  for (int o = 1; o < 256; o <<= 1){
    int a = (t >= o) ? s[t-o] : 0;
    __syncthreads();
    s[t] += a;
    __syncthreads();
  }
  if (t == 255) basev = atomicAdd(cursor, s[255]);
  __syncthreads();
  if (i < NN){
    int ex = basev + s[t] - v;
    rowp[i] = ex; curp[i] = ex;
  }
}

// ---------------- combined CSR fill: interleaved (col,val) int2 -> ONE 8B store/edge ----------------
__global__ void k_fill_all(const int* __restrict__ src_i, const int* __restrict__ dst_i,
                           const float* __restrict__ ea,
                           const int* __restrict__ src_e, const int* __restrict__ dst_e,
                           const float* __restrict__ pos,
                           int* __restrict__ cur_i, int2* __restrict__ ev_i,
                           int* __restrict__ cur_e, int2* __restrict__ ev_e){
  int e = blockIdx.x*256 + threadIdx.x;
  if (e < EIN){
    int d = dst_i[e];
    int slot = atomicAdd(&cur_i[d], 1);
    ev_i[slot] = make_int2(src_i[e], __float_as_int(ea[e]));
  } else if (e < EIN + EEX){
    int ee = e - EIN;
    int s = src_e[ee], d = dst_e[ee];
    float dx = pos[3*s+0] - pos[3*d+0];
    float dy = pos[3*s+1] - pos[3*d+1];
    float dz = pos[3*s+2] - pos[3*d+2];
    float w = __expf(-(dx*dx + dy*dy + dz*dz));
    int slot = atomicAdd(&cur_e[d], 1);
    ev_e[slot] = make_int2(s, __float_as_int(w));
  }
}

// ---------------- gather (fp8 mirror, int2 edge pairs, packed f32 FMA) ----------------
#define GATHER8_BODY                                                                  \
  {                                                                                   \
    const int slot = tid >> 4;                                                        \
    const int l16  = tid & 15;                                                        \
    const int j8 = l16 * 8;                                                           \
    const int n = n0 + slot;                                                          \
    _Pragma("unroll")                                                                 \
    for (int list = 0; list < 2; ++list){                                             \
      const int*  rowp = list ? rowE : rowI;                                          \
      const int*  cntp = list ? cntE : cntI;                                          \
      const int2* evp  = list ? evE  : evI;                                           \
      f2v a01 = {0.f,0.f}, a23 = {0.f,0.f}, a45 = {0.f,0.f}, a67 = {0.f,0.f};         \
      const int s = rowp[n], c = cntp[n];                                             \
      int t = 0;                                                                      \
      for (; t + 4 <= c; t += 4){                                                     \
        int2 e0 = evp[s+t+0], e1 = evp[s+t+1], e2 = evp[s+t+2], e3 = evp[s+t+3];      \
        uint2 qq[4];                                                                  \
        qq[0] = *(const uint2*)(hin8 + (size_t)e0.x*H + j8);                          \
        qq[1] = *(const uint2*)(hin8 + (size_t)e1.x*H + j8);                          \
        qq[2] = *(const uint2*)(hin8 + (size_t)e2.x*H + j8);                          \
        qq[3] = *(const uint2*)(hin8 + (size_t)e3.x*H + j8);                          \
        const float vvv[4] = {__int_as_float(e0.y), __int_as_float(e1.y),             \
                              __int_as_float(e2.y), __int_as_float(e3.y)};            \
        _Pragma("unroll")                                                             \
        for (int u = 0; u < 4; ++u){                                                  \
          const f2v x01 = __builtin_amdgcn_cvt_pk_f32_fp8((int)qq[u].x, false);       \
          const f2v x23 = __builtin_amdgcn_cvt_pk_f32_fp8((int)qq[u].x, true);        \
          const f2v x45 = __builtin_amdgcn_cvt_pk_f32_fp8((int)qq[u].y, false);       \
          const f2v x67 = __builtin_amdgcn_cvt_pk_f32_fp8((int)qq[u].y, true);        \
          a01 += x01 * vvv[u];                                                        \
          a23 += x23 * vvv[u];                                                        \
          a45 += x45 * vvv[u];                                                        \
          a67 += x67 * vvv[u];                                                        \
        }                                                                             \
      }                                                                               \
      for (; t < c; ++t){                                                             \
        const int2 e0 = evp[s+t];                                                     \
        const float v0 = __int_as_float(e0.y);                                        \
        const uint2 q0 = *(const uint2*)(hin8 + (size_t)e0.x*H + j8);                 \
        const f2v x01 = __builtin_amdgcn_cvt_pk_f32_fp8((int)q0.x, false);            \
        const f2v x23 = __builtin_amdgcn_cvt_pk_f32_fp8((int)q0.x, true);             \
        const f2v x45 = __builtin_amdgcn_cvt_pk_f32_fp8((int)q0.y, false);            \
        const f2v x67 = __builtin_amdgcn_cvt_pk_f32_fp8((int)q0.y, true);             \
        a01 += x01 * v0;                                                              \
        a23 += x23 * v0;                                                              \
        a45 += x45 * v0;                                                              \
        a67 += x67 * v0;                                                              \
      }                                                                               \
      const unsigned p0 = (unsigned)f2bf(a01.x) | ((unsigned)f2bf(a01.y) << 16);      \
      const unsigned p1 = (unsigned)f2bf(a23.x) | ((unsigned)f2bf(a23.y) << 16);      \
      const unsigned p2 = (unsigned)f2bf(a45.x) | ((unsigned)f2bf(a45.y) << 16);      \
      const unsigned p3 = (unsigned)f2bf(a67.x) | ((unsigned)f2bf(a67.y) << 16);      \
      u16* drow = list ? &aggEs[slot][j8] : &aggIs[slot][j8];                         \
      *(uint4*)drow = make_uint4(p0, p1, p2, p3);                                     \
    }                                                                                 \
  }

#define MFMA_BODY                                                                     \
  f4v accIA = {0.f,0.f,0.f,0.f}, accIB = {0.f,0.f,0.f,0.f};                           \
  f4v accEA = {0.f,0.f,0.f,0.f}, accEB = {0.f,0.f,0.f,0.f};                           \
  _Pragma("unroll")                                                                   \
  for (int kc = 0; kc < 4; ++kc){                                                     \
    const int koff = kc*32 + quad*8;                                                  \
    const s8v aI = *(const s8v*)&aggIs[col][koff];                                    \
    const s8v aE = *(const s8v*)&aggEs[col][koff];                                    \
    const s8v bIA = *(const s8v*)(WfI + (((jta*4 + kc)*64 + lane) << 3));             \
    const s8v bIB = *(const s8v*)(WfI + (((jtb*4 + kc)*64 + lane) << 3));             \
    const s8v bEA = *(const s8v*)(WfE + (((jta*4 + kc)*64 + lane) << 3));             \
    const s8v bEB = *(const s8v*)(WfE + (((jtb*4 + kc)*64 + lane) << 3));             \
    accIA = __builtin_amdgcn_mfma_f32_16x16x32_bf16(aI, bIA, accIA, 0, 0, 0);         \
    accIB = __builtin_amdgcn_mfma_f32_16x16x32_bf16(aI, bIB, accIB, 0, 0, 0);         \
    accEA = __builtin_amdgcn_mfma_f32_16x16x32_bf16(aE, bEA, accEA, 0, 0, 0);         \
    accEB = __builtin_amdgcn_mfma_f32_16x16x32_bf16(aE, bEB, accEB, 0, 0, 0);         \
  }

// ---------------- layers 1..2: read state, write hout + fp8 mirror ----------------
__global__ __launch_bounds__(256) void k_layer(
    const u16* __restrict__ hin, const u8* __restrict__ hin8,
    u16* __restrict__ hout, u8* __restrict__ hout8,
    u16* __restrict__ vp, u16* __restrict__ vl,
    const int* __restrict__ rowI, const int* __restrict__ cntI,
    const int2* __restrict__ evI,
    const int* __restrict__ rowE, const int* __restrict__ cntE,
    const int2* __restrict__ evE,
    const u16* __restrict__ WfI, const float* __restrict__ bI,
    const u16* __restrict__ WfE, const float* __restrict__ bE)
{
  __shared__ u16 aggIs[TM][136];
  __shared__ u16 aggEs[TM][136];
  const int n0 = blockIdx.x * TM;
  const int tid = threadIdx.x;

  GATHER8_BODY
  __syncthreads();

  const int lane = tid & 63;
  const int w    = tid >> 6;
  const int jta = 2*w, jtb = 2*w + 1;
  const int col  = lane & 15;
  const int quad = lane >> 4;
  MFMA_BODY

  #pragma unroll
  for (int r = 0; r < 4; ++r){
    const int m = quad*4 + r;
    const int n = n0 + m;
    const float cI = (float)cntI[n];
    const float cE = (float)cntE[n];
    const float rdI = 1.0f / (cI + 1.0f);
    const float ldE = logf(cE + 1.0f);
    #pragma unroll
    for (int half = 0; half < 2; ++half){
      const int j = (half ? jtb : jta)*16 + col;
      const float aIv = half ? accIB[r] : accIA[r];
      const float aEv = half ? accEB[r] : accEA[r];
      const float mi = (aIv + cI*bI[j]) * rdI;
      const float me = (aEv + cE*bE[j]) * ldE;
      const size_t idx = (size_t)n*H + j;
      const float vpn = silu_f(mi + bf2f(vp[idx]));
      const float vln = silu_f(me + bf2f(vl[idx]));
      vp[idx] = f2bf(vpn); vl[idx] = f2bf(vln);
      const float hnew = bf2f(hin[idx]) + vpn + vln;
      hout[idx] = f2bf(hnew);
      hout8[idx] = f2fp8(hnew);
    }
  }
}

// ---------------- layer 0: state store-only (no vp/vl read, no memset needed) ----------------
__global__ __launch_bounds__(256) void k_layer0(
    const u16* __restrict__ hin, const u8* __restrict__ hin8,
    u16* __restrict__ hout, u8* __restrict__ hout8,
    u16* __restrict__ vp, u16* __restrict__ vl,
    const int* __restrict__ rowI, const int* __restrict__ cntI,
    const int2* __restrict__ evI,
    const int* __restrict__ rowE, const int* __restrict__ cntE,
    const int2* __restrict__ evE,
    const u16* __restrict__ WfI, const float* __restrict__ bI,
    const u16* __restrict__ WfE, const float* __restrict__ bE)
{
  __shared__ u16 aggIs[TM][136];
  __shared__ u16 aggEs[TM][136];
  const int n0 = blockIdx.x * TM;
  const int tid = threadIdx.x;

  GATHER8_BODY
  __syncthreads();

  const int lane = tid & 63;
  const int w    = tid >> 6;
  const int jta = 2*w, jtb = 2*w + 1;
  const int col  = lane & 15;
  const int quad = lane >> 4;
  MFMA_BODY

  #pragma unroll
  for (int r = 0; r < 4; ++r){
    const int m = quad*4 + r;
    const int n = n0 + m;
    const float cI = (float)cntI[n];
    const float cE = (float)cntE[n];
    const float rdI = 1.0f / (cI + 1.0f);
    const float ldE = logf(cE + 1.0f);
    #pragma unroll
    for (int half = 0; half < 2; ++half){
      const int j = (half ? jtb : jta)*16 + col;
      const float aIv = half ? accIB[r] : accIA[r];
      const float aEv = half ? accEB[r] : accEA[r];
      const float mi = (aIv + cI*bI[j]) * rdI;
      const float me = (aEv + cE*bE[j]) * ldE;
      const size_t idx = (size_t)n*H + j;
      const float vpn = silu_f(mi);      // vp/vl start at zero: no read
      const float vln = silu_f(me);
      vp[idx] = f2bf(vpn); vl[idx] = f2bf(vln);
      const float hnew = bf2f(hin[idx]) + vpn + vln;
      hout[idx] = f2bf(hnew);
      hout8[idx] = f2fp8(hnew);
    }
  }
}

// ---------------- layer 3: NO state stores; pool fused from registers ----------------
__global__ __launch_bounds__(256) void k_layer3(
    const u16* __restrict__ hin, const u8* __restrict__ hin8,
    u16* __restrict__ vp, u16* __restrict__ vl,
    const int* __restrict__ rowI, const int* __restrict__ cntI,
    const int2* __restrict__ evI,
    const int* __restrict__ rowE, const int* __restrict__ cntE,
    const int2* __restrict__ evE,
    const u16* __restrict__ WfI, const float* __restrict__ bI,
    const u16* __restrict__ WfE, const float* __restrict__ bE,
    const int* __restrict__ batch, float* __restrict__ gp)
{
  __shared__ u16 aggIs[TM][136];
  __shared__ u16 aggEs[TM][136];
  const int n0 = blockIdx.x * TM;
  const int tid = threadIdx.x;

  GATHER8_BODY
  __syncthreads();

  const int lane = tid & 63;
  const int w    = tid >> 6;
  const int jta = 2*w, jtb = 2*w + 1;
  const int col  = lane & 15;
  const int quad = lane >> 4;
  MFMA_BODY

  float hf0[4], hf1[4];
  #pragma unroll
  for (int r = 0; r < 4; ++r){
    const int m = quad*4 + r;
    const int n = n0 + m;
    const float cI = (float)cntI[n];
    const float cE = (float)cntE[n];
    const float rdI = 1.0f / (cI + 1.0f);
    const float ldE = logf(cE + 1.0f);
    const int j0 = jta*16 + col;
    const int j1 = jtb*16 + col;
    const size_t i0 = (size_t)n*H + j0;
    const size_t i1 = (size_t)n*H + j1;
    const float mi0 = (accIA[r] + cI*bI[j0]) * rdI;
    const float me0 = (accEA[r] + cE*bE[j0]) * ldE;
    const float mi1 = (accIB[r] + cI*bI[j1]) * rdI;
    const float me1 = (accEB[r] + cE*bE[j1]) * ldE;
    const float vpn0 = silu_f(mi0 + bf2f(vp[i0]));
    const float vln0 = silu_f(me0 + bf2f(vl[i0]));
    const float vpn1 = silu_f(mi1 + bf2f(vp[i1]));
    const float vln1 = silu_f(me1 + bf2f(vl[i1]));
    hf0[r] = bf2f(hin[i0]) + vpn0 + vln0;
    hf1[r] = bf2f(hin[i1]) + vpn1 + vln1;
  }

  const int j0g = jta*16 + col;
  const int j1g = jtb*16 + col;
  const int b0 = batch[n0];
  const int b15 = batch[n0 + TM - 1];
  if (b0 == b15){
    float s0 = hf0[0] + hf0[1] + hf0[2] + hf0[3];
    float s1 = hf1[0] + hf1[1] + hf1[2] + hf1[3];
    s0 += __shfl_xor(s0, 16, 64); s0 += __shfl_xor(s0, 32, 64);
    s1 += __shfl_xor(s1, 16, 64); s1 += __shfl_xor(s1, 32, 64);
    if (quad == 0){
      atomicAdd(&gp[(size_t)b0*H + j0g], s0);
      atomicAdd(&gp[(size_t)b0*H + j1g], s1);
    }
  } else {
    #pragma unroll
    for (int r = 0; r < 4; ++r){
      const int bcur = batch[n0 + quad*4 + r];
      atomicAdd(&gp[(size_t)bcur*H + j0g], hf0[r]);
      atomicAdd(&gp[(size_t)bcur*H + j1g], hf1[r]);
    }
  }
}

// ---------------- FC head ----------------
__global__ void k_fc(const float* __restrict__ g, const float* __restrict__ fcW,
                     const float* __restrict__ fcb, const float* __restrict__ gamma,
                     const float* __restrict__ beta, const float* __restrict__ outW,
                     const float* __restrict__ outb, float* __restrict__ out){
  __shared__ float row[H];
  __shared__ float red[H];
  const int gi = blockIdx.x;
  const int j = threadIdx.x;
  row[j] = g[(size_t)gi*H + j];
  __syncthreads();
  const float bn_scale = rsqrtf(1.0f + 1e-5f);
  for (int l = 0; l < 3; ++l){
    const float* W = fcW + (size_t)l*H*H;
    float acc = fcb[l*H + j];
    #pragma unroll 8
    for (int k = 0; k < H; ++k) acc += row[k] * W[k*H + j];
    acc = (acc > 0.f) ? acc : 0.01f*acc;             // leaky_relu
    acc = acc * bn_scale * gamma[l*H + j] + beta[l*H + j];
    __syncthreads();
    row[j] = acc;
    __syncthreads();
  }
  red[j] = row[j] * outW[j];
  __syncthreads();
  for (int o = 64; o > 0; o >>= 1){
    if (j < o) red[j] += red[j + o];
    __syncthreads();
  }
  if (j == 0) out[gi] = red[0] + outb[0];
}

extern "C" void kernel_launch(void* const* d_in, const int* in_sizes, int n_in,
                              void* d_out, int out_size, void* d_ws, size_t ws_size,
                              hipStream_t stream)
{
  const float* x    = (const float*)d_in[0];
  const int*   eii  = (const int*)  d_in[1];
  const int*   eie  = (const int*)  d_in[2];
  const float* pos  = (const float*)d_in[3];
  const float* ea   = (const float*)d_in[4];
  const int*   batch= (const int*)  d_in[5];
  const float* lnW  = (const float*)d_in[6];
  const float* lnb  = (const float*)d_in[7];
  const float* WIa  = (const float*)d_in[8];
  const float* bIa  = (const float*)d_in[9];
  const float* WEa  = (const float*)d_in[10];
  const float* bEa  = (const float*)d_in[11];
  const float* fcW  = (const float*)d_in[12];
  const float* fcb  = (const float*)d_in[13];
  const float* gam  = (const float*)d_in[14];
  const float* bet  = (const float*)d_in[15];
  const float* outW = (const float*)d_in[16];
  const float* outb = (const float*)d_in[17];
  float* out = (float*)d_out;

  const int* src_i = eii;  const int* dst_i = eii + EIN;
  const int* src_e = eie;  const int* dst_e = eie + EEX;

  const size_t NH = (size_t)NN * H;
  u16* hA = (u16*)d_ws;                    // NH
  u16* hB = hA + NH;
  u16* vp = hB + NH;
  u16* vl = vp + NH;
  u8* hA8 = (u8*)(vl + NH);                // NH bytes
  u8* hB8 = hA8 + NH;
  float* gp = (float*)(hB8 + NH);          // NG*H
  int* cnt_i = (int*)(gp + (size_t)NG*H);  // NN
  int* cnt_e = cnt_i + NN;
  int* cursors = cnt_e + NN;               // 4 ints
  int* row_i = cursors + 4;
  int* row_e = row_i + NN;
  int* cur_i = row_e + NN;
  int* cur_e = cur_i + NN;
  int2* ev_i = (int2*)(cur_e + NN);        // EIN int2 (8B-aligned: offset even)
  int2* ev_e = ev_i + EIN;                 // EEX int2
  u16* WfI = (u16*)(ev_e + EEX);           // NL*H*H bf16
  u16* WfE = WfI + (size_t)NL*H*H;

  const size_t need = 4*NH*sizeof(u16) + 2*NH
                    + ((size_t)NG*H + 6*(size_t)NN + 4)*4
                    + ((size_t)EIN + (size_t)EEX)*8
                    + 2*(size_t)NL*H*H*sizeof(u16);
  if (ws_size < need) return;

  // memset: gp + cnt_i + cnt_e + cursors (contiguous)
  hipMemsetAsync(gp, 0, ((size_t)NG*H + 2*(size_t)NN + 4)*sizeof(int), stream);

  const int NE_ALL = EIN + EEX;
  const int NBC = (NE_ALL + 255)/256;      // 4688 count blocks
  k_prep<<<2*NL + NN/TML + NBC, 256, 0, stream>>>(x, lnW, lnb, hA, hA8, WIa, WEa, WfI, WfE,
                                                  dst_i, dst_e, cnt_i, cnt_e);

  const int NB = (NN + 255)/256;  // 391
  k_scan_fused<<<2*NB, 256, 0, stream>>>(cnt_i, cnt_e, row_i, cur_i, row_e, cur_e, cursors);
  k_fill_all<<<NBC, 256, 0, stream>>>(src_i, dst_i, ea, src_e, dst_e, pos,
                                      cur_i, ev_i, cur_e, ev_e);

  // L0: hA->hB ; L1: hB->hA ; L2: hA->hB ; L3: reads hB, pools into gp
  k_layer0<<<NTILES, 256, 0, stream>>>(hA, hA8, hB, hB8, vp, vl,
      row_i, cnt_i, ev_i, row_e, cnt_e, ev_e,
      WfI + 0*(size_t)H*H, bIa + 0*H, WfE + 0*(size_t)H*H, bEa + 0*H);
  k_layer<<<NTILES, 256, 0, stream>>>(hB, hB8, hA, hA8, vp, vl,
      row_i, cnt_i, ev_i, row_e, cnt_e, ev_e,
      WfI + 1*(size_t)H*H, bIa + 1*H, WfE + 1*(size_t)H*H, bEa + 1*H);
  k_layer<<<NTILES, 256, 0, stream>>>(hA, hA8, hB, hB8, vp, vl,
      row_i, cnt_i, ev_i, row_e, cnt_e, ev_e,
      WfI + 2*(size_t)H*H, bIa + 2*H, WfE + 2*(size_t)H*H, bEa + 2*H);
  k_layer3<<<NTILES, 256, 0, stream>>>(hB, hB8, vp, vl,
      row_i, cnt_i, ev_i, row_e, cnt_e, ev_e,
      WfI + 3*(size_t)H*H, bIa + 3*H, WfE + 3*(size_t)H*H, bEa + 3*H,
      batch, gp);

  k_fc<<<NG, H, 0, stream>>>(gp, fcW, fcb, gam, bet, outW, outb, out);
}